// Round 6
// baseline (235.903 us; speedup 1.0000x reference)
//
#include <hip/hip_runtime.h>
#include <hip/hip_bf16.h>

// B=2, L=4096, D=768, H=12, HS=64, SCALE=0.125. Inputs/outputs fp32; bf16 MFMA inside.
#define LQ 4096
#define DQ 768
#define NH 12
#define NB 2

typedef __attribute__((ext_vector_type(8))) short short8;
typedef __attribute__((ext_vector_type(2))) unsigned uint2v;
typedef __attribute__((ext_vector_type(4))) unsigned uint4v;
typedef __attribute__((ext_vector_type(4))) float f32x4;

__device__ __forceinline__ short f2bf(float f) {
    union { float f; unsigned u; } v; v.f = f;
    unsigned r = v.u + 0x7FFFu + ((v.u >> 16) & 1u);   // RNE
    return (short)(r >> 16);
}

__device__ __forceinline__ unsigned pk2(float a, float b) {
    float2 t; t.x = a; t.y = b;
    __hip_bfloat162 h = __float22bfloat162_rn(t);
    unsigned u; __builtin_memcpy(&u, &h, 4);
    return u;
}

__device__ __forceinline__ f32x4 mfma16(short8 a, short8 b, f32x4 c) {
    return __builtin_amdgcn_mfma_f32_16x16x32_bf16(a, b, c, 0, 0, 0);
}

// async 16B global->LDS DMA (dest = wave-uniform base + lane*16)
__device__ __forceinline__ void gld16(const short* g, short* l) {
    __builtin_amdgcn_global_load_lds(
        (const __attribute__((address_space(1))) unsigned int*)(g),
        (__attribute__((address_space(3))) unsigned int*)(l), 16, 0, 0);
}

// sqrt(0.125 * log2(e)): Qf pre-scaled so S^T = (Q')(Q')^T is directly in exp2 domain
#define SQRT_C 0.424660891f

// Fragment-major layouts (per bh, per 64-key tile = 4096 shorts, 8 chunks of 512):
//  Qf chunk(t4,s): lane L holds Q[key=16*t4+(L&15)][d=32*s+8*(L>>4)+j]  (SCALED by SQRT_C)
//  Vf chunk(t2,ks): lane L holds Q[key=32*ks+8*(L>>4)+j][d=16*t2+(L&15)] (unscaled)
// Chunk layout is LINEAR in key: 32-key sub-tile kb reads Qf at kb*2048 + (t4*2+s)*512.

// C[M,N] = A[M,K] @ W[N,K]^T, M=8192, N=768, K=768.
// ROUND-6: cvtw passes FUSED into the gemms (6 kernel dispatches -> 3). Three different
// K-loop structures all gave the same total => suspected fixed per-dispatch overhead +
// memory round-trips, not K-loop time. W is staged from fp32 with in-register cvt
// (round-2-proven float4->pk2->ds_write); MODE 1 also stages A from fp32 x the same way.
// MODE 0 keeps gld16 DMA for A (bf16 attn output). Geometry unchanged from round 5:
// BM=128, BN=192, BK=64, 512 threads = 8 waves (2m x 4n), 64x48 out/wave, 256 blocks
// = 1/CU, XCD-affine mt. LDS 80KB double-buffered, G21 XOR swizzle (source chunk
// k ^ (row&7), linear LDS write, reads un-swizzle). Single barrier per kt: reg-staged
// writes go to the OTHER buffer before the barrier (no WAR hazard).
// MODE 0: C fp32 row-major. MODE 1: BN=192 = 3 heads -> per-head F slabs, fragment
// scatter identical to round 5 (verified).
template <int MODE>
__global__ __launch_bounds__(512, 2) void gemm_nt(const short* __restrict__ Abf,
                                                  const float* __restrict__ Axf,
                                                  const float* __restrict__ Wf,
                                                  void* __restrict__ Cp,
                                                  short* __restrict__ Vf) {
    // carve: As[2][8192] = smem[0..16384), Bs[2][12288] = smem[16384..40960)
    __shared__ __attribute__((aligned(16))) short smem[40960];   // 80 KB
    const int t = threadIdx.x;
    const int lane = t & 63, w = t >> 6;                 // 8 waves
    const int lr = lane & 15, qd = lane >> 4;
    const int wm = (w >> 2) * 64, wn = (w & 3) * 48;     // wave tile 64m x 48n
    const int lin = blockIdx.x;
    const int xcd = lin & 7, jj = lin >> 3;              // 256 blocks, 8 XCDs
    const int nt = jj & 3, mt = (jj >> 2) * 8 + xcd;     // 4 n-tiles x 64 m-tiles
    const int m0 = mt * 128, n0 = nt * 192;

    // kt-invariant per-lane/thread source offsets (XOR-swizzled chunk within 8-chunk row)
    // A (MODE 0, DMA): wave-cooperative units. A (MODE 1) / B: per-thread chunks.
    int aoffs[2];
    if (MODE == 0) {
#pragma unroll
        for (int u = 0; u < 2; ++u) {
            int c = (u * 8 + w) * 64 + lane;             // A 16B-unit id 0..1023
            int row = c >> 3, k = (c & 7) ^ (row & 7);
            aoffs[u] = (m0 + row) * DQ + k * 8;
        }
    } else {
#pragma unroll
        for (int u = 0; u < 2; ++u) {
            int c = t + 512 * u;                         // A chunk id 0..1023
            int row = c >> 3, k = (c & 7) ^ (row & 7);
            aoffs[u] = (m0 + row) * DQ + k * 8;
        }
    }
    int boffs[3], bdst[3];
#pragma unroll
    for (int u = 0; u < 3; ++u) {
        int c = t + 512 * u;                             // B chunk id 0..1535
        int row = c >> 3, k = (c & 7) ^ (row & 7);
        boffs[u] = (n0 + row) * DQ + k * 8;
        bdst[u] = c * 8;
    }

    f32x4 acc[4][3];
#pragma unroll
    for (int i = 0; i < 4; ++i)
#pragma unroll
        for (int j = 0; j < 3; ++j) acc[i][j] = (f32x4){0.f, 0.f, 0.f, 0.f};

    // ---- prologue: stage kt=0 into buffer 0 ----
    if (MODE == 0) {
#pragma unroll
        for (int u = 0; u < 2; ++u) gld16(&Abf[aoffs[u]], &smem[(u * 8 + w) * 512]);
    } else {
#pragma unroll
        for (int u = 0; u < 2; ++u) {
            float4 lo = *(const float4*)&Axf[aoffs[u]];
            float4 hi = *(const float4*)&Axf[aoffs[u] + 4];
            *(uint4v*)&smem[(t + 512 * u) * 8] =
                (uint4v){pk2(lo.x, lo.y), pk2(lo.z, lo.w), pk2(hi.x, hi.y), pk2(hi.z, hi.w)};
        }
    }
#pragma unroll
    for (int u = 0; u < 3; ++u) {
        float4 lo = *(const float4*)&Wf[boffs[u]];
        float4 hi = *(const float4*)&Wf[boffs[u] + 4];
        *(uint4v*)&smem[16384 + bdst[u]] =
            (uint4v){pk2(lo.x, lo.y), pk2(lo.z, lo.w), pk2(hi.x, hi.y), pk2(hi.z, hi.w)};
    }
    __syncthreads();

    int cur = 0;
    for (int kt = 0; kt < 12; ++kt) {
        float4 fa[2][2], fb[3][2];
        if (kt < 11) {                                   // issue next-tile loads first
            const int k0 = (kt + 1) * 64;
            if (MODE == 0) {
#pragma unroll
                for (int u = 0; u < 2; ++u)
                    gld16(&Abf[aoffs[u] + k0], &smem[(cur ^ 1) * 8192 + (u * 8 + w) * 512]);
            } else {
#pragma unroll
                for (int u = 0; u < 2; ++u) {
                    fa[u][0] = *(const float4*)&Axf[aoffs[u] + k0];
                    fa[u][1] = *(const float4*)&Axf[aoffs[u] + k0 + 4];
                }
            }
#pragma unroll
            for (int u = 0; u < 3; ++u) {
                fb[u][0] = *(const float4*)&Wf[boffs[u] + k0];
                fb[u][1] = *(const float4*)&Wf[boffs[u] + k0 + 4];
            }
        }
        const short* Asb = &smem[cur * 8192];
        const short* Bsb = &smem[16384 + cur * 12288];
#pragma unroll
        for (int s = 0; s < 2; ++s) {
            const int cq = ((4 * s + qd) ^ (lr & 7)) * 8;    // un-swizzle chunk position
            short8 af[4], bf[3];
#pragma unroll
            for (int i = 0; i < 4; ++i)
                af[i] = *(const short8*)&Asb[(wm + 16 * i + lr) * 64 + cq];
#pragma unroll
            for (int j = 0; j < 3; ++j)
                bf[j] = *(const short8*)&Bsb[(wn + 16 * j + lr) * 64 + cq];
#pragma unroll
            for (int i = 0; i < 4; ++i)
#pragma unroll
                for (int j = 0; j < 3; ++j)
                    acc[i][j] = mfma16(af[i], bf[j], acc[i][j]);
        }
        if (kt < 11) {                                   // cvt+write into the OTHER buffer
            if (MODE == 1) {
#pragma unroll
                for (int u = 0; u < 2; ++u)
                    *(uint4v*)&smem[(cur ^ 1) * 8192 + (t + 512 * u) * 8] =
                        (uint4v){pk2(fa[u][0].x, fa[u][0].y), pk2(fa[u][0].z, fa[u][0].w),
                                 pk2(fa[u][1].x, fa[u][1].y), pk2(fa[u][1].z, fa[u][1].w)};
            }
#pragma unroll
            for (int u = 0; u < 3; ++u)
                *(uint4v*)&smem[16384 + (cur ^ 1) * 12288 + bdst[u]] =
                    (uint4v){pk2(fb[u][0].x, fb[u][0].y), pk2(fb[u][0].z, fb[u][0].w),
                             pk2(fb[u][1].x, fb[u][1].y), pk2(fb[u][1].z, fb[u][1].w)};
        }
        __syncthreads();                                 // drains DMA + ds_write + read-sync
        cur ^= 1;
    }

    if (MODE == 0) {
#pragma unroll
        for (int i = 0; i < 4; ++i)
#pragma unroll
            for (int j = 0; j < 3; ++j) {
                const int row0 = m0 + wm + 16 * i + qd * 4;
                const int col = n0 + wn + 16 * j + lr;
#pragma unroll
                for (int r = 0; r < 4; ++r)
                    ((float*)Cp)[(size_t)(row0 + r) * DQ + col] = acc[i][j][r];
            }
    } else {
        // block tile = keys kl0..kl0+127 of 3 heads {nt*3, +1, +2} of batch m0>>12.
        short* Qf = (short*)Cp;
        short* F = smem;                                 // 24576-short scratch [3][8192]
        const int bh0 = (m0 >> 12) * NH + nt * 3;
        const int kl0 = m0 & 4095;
        // ---- Vf staging (unscaled): packed b64 scatter ----
#pragma unroll
        for (int i = 0; i < 4; ++i)
#pragma unroll
            for (int j = 0; j < 3; ++j) {
                const int kl = wm + 16 * i + qd * 4;     // key 0..127 (4 consecutive)
                const int hsg = wn + 16 * j + lr;        // global d 0..191
                const int hh = hsg >> 6, hs = hsg & 63;
                const int fi = hh * 8192 + ((kl >> 6) & 1) * 4096
                             + ((((hs >> 4) << 1) + ((kl >> 5) & 1)) << 9)
                             + (((hs & 15) + (((kl >> 3) & 3) << 4)) << 3) + (kl & 7);
                *(uint2v*)&F[fi] = (uint2v){pk2(acc[i][j][0], acc[i][j][1]),
                                            pk2(acc[i][j][2], acc[i][j][3])};
            }
        __syncthreads();
#pragma unroll
        for (int p = 0; p < 6; ++p) {
            int u = t + 512 * p;                         // atom id 0..3071
            int hh = u >> 10, rem = u & 1023;
            size_t g = (size_t)(bh0 + hh) * (LQ * 64) + (size_t)((kl0 >> 6) << 12);
            *(short8*)&Vf[g + (size_t)rem * 8] = *(short8*)&F[u * 8];
        }
        __syncthreads();
        // ---- Qf staging (scaled by SQRT_C): b16 scatter ----
#pragma unroll
        for (int i = 0; i < 4; ++i)
#pragma unroll
            for (int j = 0; j < 3; ++j) {
                const int hsg = wn + 16 * j + lr;
                const int hh = hsg >> 6, hs = hsg & 63;
#pragma unroll
                for (int r = 0; r < 4; ++r) {
                    const int key = wm + 16 * i + qd * 4 + r;
                    const int fi = hh * 8192 + ((key >> 6) & 1) * 4096
                                 + (((((key >> 4) & 3) << 1) + (hs >> 5)) << 9)
                                 + (((qd * 4 + r) + (((hs >> 3) & 3) << 4)) << 3) + (hs & 7);
                    F[fi] = f2bf(acc[i][j][r] * SQRT_C);
                }
            }
        __syncthreads();
#pragma unroll
        for (int p = 0; p < 6; ++p) {
            int u = t + 512 * p;
            int hh = u >> 10, rem = u & 1023;
            size_t g = (size_t)(bh0 + hh) * (LQ * 64) + (size_t)((kl0 >> 6) << 12);
            *(short8*)&Qf[g + (size_t)rem * 8] = *(short8*)&F[u * 8];
        }
    }
}

// Split-K-in-block flash attention, K=V=Q, shift-0 softmax, fragment-major loads.
// 4-wave (256t) blocks = {2 q-groups of 64q} x {2 key-halves of 2048k}; 768 blocks
// = 3 blocks/CU = 12 waves/CU. Register budget (256,3) = ~170 unified regs/wave.
// PROVEN at 129-133us (rounds 2/4/5, cross-run noise +-3us); round-3 showed explicit
// prefetch only hurts -- with no barriers in the loop the compiler already hoists
// loads maximally. FROZEN this round as the control for the dispatch-overhead test.
// Phase-separated so kf and vb register lifetimes never overlap.
// Shift-0 softmax => partial (O,l) over disjoint key ranges combine by pure addition:
// epilogue LDS exchange (fp32, stride 21*16B, conflict-free), half=0 waves add+normalize.
__global__ __launch_bounds__(256, 3) void attn(const short* __restrict__ Qf,
                                               const short* __restrict__ Vf,
                                               short* __restrict__ O) {
    const int linear = blockIdx.x;
    const int xcd = linear & 7, slot = linear >> 3;        // 768 blocks, 8 XCDs
    const int bh = 3 * xcd + (slot >> 5);                  // 3 bh per XCD (L2-resident)
    const int qtile = slot & 31;                           // 32 q-tiles of 128
    const int t = threadIdx.x;
    const int lane = t & 63, w = t >> 6;                   // w in {0..3}
    const int qw = w & 1, half = w >> 1;                   // q-group, key-half
    const int lr = lane & 15, qd = lane >> 4;

    // LDS: aqs [2 qw][4096] shorts (16384B) + Ps [4 w][4 chains][16*40] shorts (20480B)
    // = 36864B, all aliased with the 43008B fp32 exchange buffer used after the loop.
    __shared__ alignas(16) char smem[43008];
    short* aqs = (short*)smem;                             // Q fragments, per q-group
    short* Ps = (short*)(smem + 16384) + w * 2560;         // per-wave P scratch (shorts)

    const short* Qbh = Qf + (size_t)bh * (LQ * 64);
    const short* Vbh = Vf + (size_t)bh * (LQ * 64);
    const int q0 = qtile * 128 + qw * 64;
    const int kb0 = half * 64;                             // 32-key tiles: 0..63 / 64..127

    const short one_bf = (short)0x3F80;                    // bf16 1.0
    short8 ones;
#pragma unroll
    for (int j = 0; j < 8; ++j) ones[j] = one_bf;

    // ---- stage this block's 128q Q-fragments into LDS (both q-groups, linear copy) ----
#pragma unroll
    for (int p = 0; p < 4; ++p) {
        int off = (t + 256 * p) * 8;                       // 0..8191 shorts
        *(short8*)&aqs[off] = *(const short8*)&Qbh[(size_t)qtile * 8192 + off];
    }
    __syncthreads();

    f32x4 oacc[4][4], lacc[4];
#pragma unroll
    for (int i = 0; i < 4; ++i) {
        lacc[i] = (f32x4){0.f, 0.f, 0.f, 0.f};
#pragma unroll
        for (int t2 = 0; t2 < 4; ++t2) oacc[i][t2] = (f32x4){0.f, 0.f, 0.f, 0.f};
    }

    const int aqbase = qw * 4096 + lane * 8;               // LDS index of this lane's aq

    for (int kb = kb0; kb < kb0 + 64; ++kb) {
        // ---- phase 1: K frags (32 keys) live; all 4 chains QK -> exp2 -> Ps ----
        short8 kf[2][2];
#pragma unroll
        for (int t4 = 0; t4 < 2; ++t4)
#pragma unroll
            for (int s = 0; s < 2; ++s)
                kf[t4][s] = *(const short8*)&Qbh[kb * 2048 + (t4 * 2 + s) * 512 + lane * 8];

#pragma unroll
        for (int i = 0; i < 4; ++i) {
            short8 aq0 = *(const short8*)&aqs[aqbase + i * 1024];
            short8 aq1 = *(const short8*)&aqs[aqbase + i * 1024 + 512];
            f32x4 s0 = (f32x4){0.f, 0.f, 0.f, 0.f};
            f32x4 s1 = (f32x4){0.f, 0.f, 0.f, 0.f};
            s0 = mfma16(kf[0][0], aq0, s0);
            s0 = mfma16(kf[0][1], aq1, s0);
            s1 = mfma16(kf[1][0], aq0, s1);
            s1 = mfma16(kf[1][1], aq1, s1);
            // lane holds S^T[key=16*t4+qd*4+r][q=lr], already in exp2 domain
            *(uint2v*)&Ps[i * 640 + lr * 40 + 4 * qd] =
                (uint2v){pk2(__builtin_amdgcn_exp2f(s0[0]), __builtin_amdgcn_exp2f(s0[1])),
                         pk2(__builtin_amdgcn_exp2f(s0[2]), __builtin_amdgcn_exp2f(s0[3]))};
            *(uint2v*)&Ps[i * 640 + lr * 40 + 16 + 4 * qd] =
                (uint2v){pk2(__builtin_amdgcn_exp2f(s1[0]), __builtin_amdgcn_exp2f(s1[1])),
                         pk2(__builtin_amdgcn_exp2f(s1[2]), __builtin_amdgcn_exp2f(s1[3]))};
        }

        // ---- phase 2: kf dead; V^T frags (32 keys) live; all 4 chains PV + l ----
        short8 vb[4];
#pragma unroll
        for (int t2 = 0; t2 < 4; ++t2)
            vb[t2] = *(const short8*)&Vbh[(kb >> 1) * 4096 + (kb & 1) * 512 + t2 * 1024 + lane * 8];

#pragma unroll
        for (int i = 0; i < 4; ++i) {
            short8 pa = *(short8*)&Ps[i * 640 + lr * 40 + qd * 8];
#pragma unroll
            for (int t2 = 0; t2 < 4; ++t2)
                oacc[i][t2] = mfma16(pa, vb[t2], oacc[i][t2]);
            lacc[i] = mfma16(pa, ones, lacc[i]);           // row-sum on the MFMA pipe
        }
    }

    // ---- split-K combine: half=1 waves publish fp32 partials, half=0 waves reduce ----
    __syncthreads();                                       // Ps/aqs dead from here; alias ok
    f32x4* ex = (f32x4*)smem + (qw * 64 + lane) * 21;      // stride 21: bank-conflict-free
    if (half) {
#pragma unroll
        for (int i = 0; i < 4; ++i) {
#pragma unroll
            for (int t2 = 0; t2 < 4; ++t2) ex[i * 4 + t2] = oacc[i][t2];
            ex[16 + i] = lacc[i];
        }
    }
    __syncthreads();
    if (half) return;

#pragma unroll
    for (int i = 0; i < 4; ++i) {
#pragma unroll
        for (int t2 = 0; t2 < 4; ++t2) oacc[i][t2] += ex[i * 4 + t2];
        lacc[i] += ex[16 + i];
    }

    // l for query qd*4+r is lacc[i][r] in every lane; normalize; store O[b][l][h*64+e]
    const int b = bh / NH, h = bh % NH;
#pragma unroll
    for (int i = 0; i < 4; ++i) {
        float inv[4];
#pragma unroll
        for (int r = 0; r < 4; ++r) inv[r] = 1.0f / lacc[i][r];
#pragma unroll
        for (int t2 = 0; t2 < 4; ++t2)
#pragma unroll
            for (int r = 0; r < 4; ++r) {
                int lq = q0 + 16 * i + qd * 4 + r;
                int e = h * 64 + 16 * t2 + lr;
                O[((size_t)(b * LQ + lq)) * DQ + e] = f2bf(oacc[i][t2][r] * inv[r]);
            }
    }
}

extern "C" void kernel_launch(void* const* d_in, const int* in_sizes, int n_in,
                              void* d_out, int out_size, void* d_ws, size_t ws_size,
                              hipStream_t stream) {
    (void)in_sizes; (void)n_in; (void)out_size; (void)ws_size;
    const float* x  = (const float*)d_in[0];   // fp32 [2,4096,768]
    const float* Wq = (const float*)d_in[1];   // fp32 [768,768]
    const float* Wo = (const float*)d_in[2];   // fp32 [768,768]
    float* out = (float*)d_out;                // fp32 [2,4096,768]

    const size_t NQ = (size_t)NB * NH * LQ * 64;         // 6,291,456 elements
    short* Qf  = (short*)d_ws;                           // fragment-major scaled Q
    short* Vfb = Qf + NQ;                                // fragment-major unscaled Q (V)
    short* Ows = Vfb + NQ;                               // attention out (bf16)

    // 1) Q-projection from fp32 x and fp32 Wq (cvt fused into staging)
    //    -> fragment-major Qf (scaled) + Vf
    gemm_nt<1><<<256, 512, 0, stream>>>(nullptr, x, Wq, Qf, Vfb);
    // 2) split-K flash attention (K=V=Q), 12 waves/CU -> Ows
    attn<<<768, 256, 0, stream>>>(Qf, Vfb, Ows);
    // 3) out = O @ Wo^T, fp32 Wo cvt fused into staging, fp32 store
    gemm_nt<0><<<256, 512, 0, stream>>>(Ows, nullptr, Wo, out, nullptr);
}